// Round 2
// baseline (351.966 us; speedup 1.0000x reference)
//
#include <hip/hip_runtime.h>
#include <math.h>

// Problem constants (match reference)
#define B_ROWS 2048
#define V_COLS 32000
#define SCALE_D 30.0
#define COS_MARGIN_D 0.35
#define ARC_MARGIN_D 0.5
#define EPS_D 1e-12
#define PI_D 3.14159265358979323846

// exp(SCALE*x) = exp2(x * 30*log2(e)); arg range +/-43.3 -> raw v_exp_f32 ok.
#define LOG2E_X30 43.2808512266689022212f

typedef float f32x4 __attribute__((ext_vector_type(4)));

// R10: attack the 4x gap between row-kernel read BW (~1.66 TB/s) and the
// fill-proven 6.6 TB/s. Changes vs R9:
//  - 4 blocks per row x 256 threads (8192 blocks, 8 blocks/CU resident,
//    still 32 waves/CU) -> finer scheduling granularity.
//  - Each thread issues 7-8 dwordx4 loads BACK-TO-BACK before any waitcnt:
//    7 KB outstanding per wave (~224 KB/CU), 4x the old 2-deep pipeline.
//  - Cached (non-nt) loads: preds (262 MB) nearly fits the 256 MB L3, so
//    replay iterations may re-hit; nt was forfeiting that for nothing.
//  - Per-row target value captured by the chunk-block that owns it (L2-hot)
//    -> no scattered gather in the finalize kernel.
//  - Single-block finalize kernel does fp64 tail math + mean.

#define TPB_A 256
#define CHUNKS 4
#define V4_CHUNK (V_COLS / 4 / CHUNKS)   // 2000 f32x4 per chunk
#define TAIL_T (V4_CHUNK - 7 * TPB_A)    // 208 threads do an 8th element

#define EXP30(x) __builtin_amdgcn_exp2f((x) * LOG2E_X30)

__global__ __launch_bounds__(TPB_A, 8) void cosarc_partial_kernel(
    const float* __restrict__ preds,
    const int*   __restrict__ labels,
    double*      __restrict__ partials,   // [B_ROWS * CHUNKS]
    float*       __restrict__ tgts)       // [B_ROWS]
{
    const int bid   = blockIdx.x;
    const int row   = bid >> 2;
    const int chunk = bid & 3;
    const int tid   = threadIdx.x;

    const float* rowp = preds + (size_t)row * V_COLS;
    const f32x4* p4   = (const f32x4*)rowp + chunk * V4_CHUNK;

    // Issue all loads back-to-back: 7 (or 8) dwordx4 in flight per thread.
    f32x4 v0 = p4[tid];
    f32x4 v1 = p4[tid + 1 * TPB_A];
    f32x4 v2 = p4[tid + 2 * TPB_A];
    f32x4 v3 = p4[tid + 3 * TPB_A];
    f32x4 v4 = p4[tid + 4 * TPB_A];
    f32x4 v5 = p4[tid + 5 * TPB_A];
    f32x4 v6 = p4[tid + 6 * TPB_A];
    const bool has8 = (tid < TAIL_T);
    f32x4 v7 = {0.f, 0.f, 0.f, 0.f};
    if (has8) v7 = p4[tid + 7 * TPB_A];

    // Capture the target cosine for this row if it lives in our chunk
    // (the chunk is streaming through L2 right now, so this re-read is hot).
    if (tid == 0) {
        const int l  = labels[row];
        const int c0 = chunk * (V_COLS / CHUNKS);
        if (l >= c0 && l < c0 + (V_COLS / CHUNKS)) tgts[row] = rowp[l];
    }

    // 4 independent fp32 accumulator chains (one per vector component).
    float sx, sy, sz, sw;
    sx  = EXP30(v0.x); sy  = EXP30(v0.y); sz  = EXP30(v0.z); sw  = EXP30(v0.w);
    sx += EXP30(v1.x); sy += EXP30(v1.y); sz += EXP30(v1.z); sw += EXP30(v1.w);
    sx += EXP30(v2.x); sy += EXP30(v2.y); sz += EXP30(v2.z); sw += EXP30(v2.w);
    sx += EXP30(v3.x); sy += EXP30(v3.y); sz += EXP30(v3.z); sw += EXP30(v3.w);
    sx += EXP30(v4.x); sy += EXP30(v4.y); sz += EXP30(v4.z); sw += EXP30(v4.w);
    sx += EXP30(v5.x); sy += EXP30(v5.y); sz += EXP30(v5.z); sw += EXP30(v5.w);
    sx += EXP30(v6.x); sy += EXP30(v6.y); sz += EXP30(v6.z); sw += EXP30(v6.w);
    if (has8) {
        sx += EXP30(v7.x); sy += EXP30(v7.y); sz += EXP30(v7.z); sw += EXP30(v7.w);
    }

    double sum = (double)((sx + sy) + (sz + sw));

    // wave(64) shuffle reduction in fp64
    #pragma unroll
    for (int off = 32; off > 0; off >>= 1)
        sum += __shfl_down(sum, off, 64);

    __shared__ double wave_sums[TPB_A / 64];
    const int wave = tid >> 6;
    const int lane = tid & 63;
    if (lane == 0) wave_sums[wave] = sum;
    __syncthreads();

    if (tid == 0) {
        double total = 0.0;
        #pragma unroll
        for (int w = 0; w < TPB_A / 64; ++w) total += wave_sums[w];
        partials[bid] = total;
    }
}

// Finalize: per-row fp64 tail math + global mean. One block, 1024 threads,
// 2 rows per thread; all loads coalesced (partials + tgts are dense).
__global__ __launch_bounds__(1024) void cosarc_final_kernel(
    const double* __restrict__ partials,
    const float*  __restrict__ tgts,
    float*        __restrict__ out)
{
    const int tid = threadIdx.x;
    double acc = 0.0;

    for (int r = tid; r < B_ROWS; r += 1024) {
        const double total = (partials[4 * r] + partials[4 * r + 1]) +
                             (partials[4 * r + 2] + partials[4 * r + 3]);
        const float tgt_f = tgts[r];
        // subtract the same fp32 exp term that was accumulated for the target
        const double sum_others = total - (double)EXP30(tgt_f);

        double t = (double)tgt_f;
        t = fmin(fmax(t, -1.0 + EPS_D), 1.0 - EPS_D);
        double theta = acos(t);
        theta = fmin(fmax(theta, EPS_D), PI_D - EPS_D);
        const double numerator = SCALE_D * (cos(theta + ARC_MARGIN_D) - COS_MARGIN_D);
        const double denominator = exp(numerator) + sum_others;
        acc += numerator - log(denominator);
    }

    #pragma unroll
    for (int off = 32; off > 0; off >>= 1)
        acc += __shfl_down(acc, off, 64);

    __shared__ double wave_sums[16];
    if ((tid & 63) == 0) wave_sums[tid >> 6] = acc;
    __syncthreads();

    if (tid == 0) {
        double total = 0.0;
        #pragma unroll
        for (int w = 0; w < 16; ++w) total += wave_sums[w];
        out[0] = (float)(-(total / (double)B_ROWS));
    }
}

extern "C" void kernel_launch(void* const* d_in, const int* in_sizes, int n_in,
                              void* d_out, int out_size, void* d_ws, size_t ws_size,
                              hipStream_t stream)
{
    const float* preds  = (const float*)d_in[0];
    const int*   labels = (const int*)d_in[1];
    float*       out    = (float*)d_out;

    // workspace layout: [0, 64KB) fp64 partials[8192]; [64KB, 72KB) fp32 tgts[2048]
    double* partials = (double*)d_ws;
    float*  tgts     = (float*)((char*)d_ws + B_ROWS * CHUNKS * sizeof(double));

    cosarc_partial_kernel<<<B_ROWS * CHUNKS, TPB_A, 0, stream>>>(preds, labels, partials, tgts);
    cosarc_final_kernel<<<1, 1024, 0, stream>>>(partials, tgts, out);
}

// Round 3
// 350.290 us; speedup vs baseline: 1.0048x; 1.0048x over previous
//
#include <hip/hip_runtime.h>
#include <math.h>

// Problem constants (match reference)
#define B_ROWS 2048
#define V_COLS 32000
#define SCALE_D 30.0
#define COS_MARGIN_D 0.35
#define ARC_MARGIN_D 0.5
#define EPS_D 1e-12
#define PI_D 3.14159265358979323846

// exp(SCALE*x) = exp2(x * 30*log2(e)); arg range +/-43.3 -> raw v_exp_f32 ok.
#define LOG2E_X30 43.2808512266689022212f

typedef float f32x4 __attribute__((ext_vector_type(4)));

#define TPB 1024  // one block per row; 16 waves/block

// R11: test the two exonerated-vs-guilty mechanisms from R9/R10:
//  - 8-deep load burst per thread (8 KB/wave in flight) with NO register
//    clamp (R10's launch_bounds(256,8) forced <=64 VGPR and likely
//    serialized/spilled the burst -> +25us).
//  - plain cached loads instead of nontemporal (nt was never A/B'd in the
//    ~325us lineage; if nt bypasses L2 it may ride a lower-MLP path).
// Structure otherwise identical to the verified R9: one 1024-thread block
// per row, fp32 exp chains, fp64 wave/LDS reduce, fp64 tail math in tid 0.
__global__ __launch_bounds__(TPB) void cosarc_row_kernel(
    const float* __restrict__ preds,
    const int*   __restrict__ labels,
    float*       __restrict__ row_terms)
{
    const int row = blockIdx.x;
    const int tid = threadIdx.x;
    const float* rowp = preds + (size_t)row * V_COLS;
    const f32x4* p4 = (const f32x4*)rowp;
    // 8000 f32x4 per row / 1024 threads: slots 0..6 for every thread,
    // slot 7 only for tid < 832.

    // Issue all loads back-to-back so 7-8 dwordx4 are in flight per thread
    // before the first vmcnt wait; consumption staggers the waits.
    f32x4 v0 = p4[tid];
    f32x4 v1 = p4[tid + 1 * TPB];
    f32x4 v2 = p4[tid + 2 * TPB];
    f32x4 v3 = p4[tid + 3 * TPB];
    f32x4 v4 = p4[tid + 4 * TPB];
    f32x4 v5 = p4[tid + 5 * TPB];
    f32x4 v6 = p4[tid + 6 * TPB];
    const bool has8 = (tid < (V_COLS / 4 - 7 * TPB));  // tid < 832
    f32x4 v7 = {0.f, 0.f, 0.f, 0.f};
    if (has8) v7 = p4[tid + 7 * TPB];

    #define EXP30(x) __builtin_amdgcn_exp2f((x) * LOG2E_X30)

    // 4 independent fp32 accumulator chains (one per vector component).
    float sx, sy, sz, sw;
    sx  = EXP30(v0.x); sy  = EXP30(v0.y); sz  = EXP30(v0.z); sw  = EXP30(v0.w);
    sx += EXP30(v1.x); sy += EXP30(v1.y); sz += EXP30(v1.z); sw += EXP30(v1.w);
    sx += EXP30(v2.x); sy += EXP30(v2.y); sz += EXP30(v2.z); sw += EXP30(v2.w);
    sx += EXP30(v3.x); sy += EXP30(v3.y); sz += EXP30(v3.z); sw += EXP30(v3.w);
    sx += EXP30(v4.x); sy += EXP30(v4.y); sz += EXP30(v4.z); sw += EXP30(v4.w);
    sx += EXP30(v5.x); sy += EXP30(v5.y); sz += EXP30(v5.z); sw += EXP30(v5.w);
    sx += EXP30(v6.x); sy += EXP30(v6.y); sz += EXP30(v6.z); sw += EXP30(v6.w);
    if (has8) {
        sx += EXP30(v7.x); sy += EXP30(v7.y); sz += EXP30(v7.z); sw += EXP30(v7.w);
    }

    double sum = (double)((sx + sy) + (sz + sw));

    // wave(64) shuffle reduction in fp64
    #pragma unroll
    for (int off = 32; off > 0; off >>= 1)
        sum += __shfl_down(sum, off, 64);

    __shared__ double wave_sums[TPB / 64];
    const int wave = tid >> 6;
    const int lane = tid & 63;
    if (lane == 0) wave_sums[wave] = sum;
    __syncthreads();

    if (tid == 0) {
        double total = 0.0;
        #pragma unroll
        for (int w = 0; w < TPB / 64; ++w) total += wave_sums[w];

        const float tgt_f = rowp[labels[row]];
        // subtract the same fp32 exp term that was accumulated for the target
        const double sum_others =
            total - (double)EXP30(tgt_f);

        double t = (double)tgt_f;
        t = fmin(fmax(t, -1.0 + EPS_D), 1.0 - EPS_D);
        double theta = acos(t);
        theta = fmin(fmax(theta, EPS_D), PI_D - EPS_D);
        const double numerator = SCALE_D * (cos(theta + ARC_MARGIN_D) - COS_MARGIN_D);
        const double denominator = exp(numerator) + sum_others;
        row_terms[row] = (float)(numerator - log(denominator));
    }
}

// Reduce the 2048 per-row terms to -mean.
__global__ __launch_bounds__(256) void cosarc_reduce_kernel(
    const float* __restrict__ row_terms,
    float*       __restrict__ out)
{
    const int tid = threadIdx.x;
    double s = 0.0;
    for (int i = tid; i < B_ROWS; i += 256)
        s += (double)row_terms[i];

    #pragma unroll
    for (int off = 32; off > 0; off >>= 1)
        s += __shfl_down(s, off, 64);

    __shared__ double wave_sums[4];
    if ((tid & 63) == 0) wave_sums[tid >> 6] = s;
    __syncthreads();

    if (tid == 0) {
        double total = wave_sums[0] + wave_sums[1] + wave_sums[2] + wave_sums[3];
        out[0] = (float)(-(total / (double)B_ROWS));
    }
}

extern "C" void kernel_launch(void* const* d_in, const int* in_sizes, int n_in,
                              void* d_out, int out_size, void* d_ws, size_t ws_size,
                              hipStream_t stream)
{
    const float* preds  = (const float*)d_in[0];
    const int*   labels = (const int*)d_in[1];
    float*       out    = (float*)d_out;
    float*       ws     = (float*)d_ws;   // needs B_ROWS*4 = 8 KB

    cosarc_row_kernel<<<B_ROWS, TPB, 0, stream>>>(preds, labels, ws);
    cosarc_reduce_kernel<<<1, 256, 0, stream>>>(ws, out);
}

// Round 4
// 325.029 us; speedup vs baseline: 1.0829x; 1.0777x over previous
//
#include <hip/hip_runtime.h>
#include <math.h>

// Problem constants (match reference)
#define B_ROWS 2048
#define V_COLS 32000
#define SCALE_D 30.0
#define COS_MARGIN_D 0.35
#define ARC_MARGIN_D 0.5
#define EPS_D 1e-12
#define PI_D 3.14159265358979323846

// exp(SCALE*x) = exp2(x * 30*log2(e)); arg range +/-43.3 -> raw v_exp_f32 ok.
#define LOG2E_X30 43.2808512266689022212f

typedef float f32x4 __attribute__((ext_vector_type(4)));

#define TPB 1024  // one block per row; 16 waves/block

// R12: single-variable A/B vs R11 — restore __builtin_nontemporal_load on
// the streaming reads. R10/R11 (different shapes, same cached loads) both
// regressed ~+24us vs R9's nt loads: evidence that cache-allocating reads
// on a 262MB stream pay L2/L3 eviction churn that nt bypasses. Keeps R11's
// 8-deep back-to-back load burst (8 KB/wave in flight) to also test queue
// depth WITH nt — R9 only ever ran 2-deep.
__global__ __launch_bounds__(TPB) void cosarc_row_kernel(
    const float* __restrict__ preds,
    const int*   __restrict__ labels,
    float*       __restrict__ row_terms)
{
    const int row = blockIdx.x;
    const int tid = threadIdx.x;
    const float* rowp = preds + (size_t)row * V_COLS;
    const f32x4* p4 = (const f32x4*)rowp;
    // 8000 f32x4 per row / 1024 threads: slots 0..6 for every thread,
    // slot 7 only for tid < 832.

    // Issue all loads back-to-back so 7-8 dwordx4 are in flight per thread
    // before the first vmcnt wait; consumption staggers the waits.
    f32x4 v0 = __builtin_nontemporal_load(&p4[tid]);
    f32x4 v1 = __builtin_nontemporal_load(&p4[tid + 1 * TPB]);
    f32x4 v2 = __builtin_nontemporal_load(&p4[tid + 2 * TPB]);
    f32x4 v3 = __builtin_nontemporal_load(&p4[tid + 3 * TPB]);
    f32x4 v4 = __builtin_nontemporal_load(&p4[tid + 4 * TPB]);
    f32x4 v5 = __builtin_nontemporal_load(&p4[tid + 5 * TPB]);
    f32x4 v6 = __builtin_nontemporal_load(&p4[tid + 6 * TPB]);
    const bool has8 = (tid < (V_COLS / 4 - 7 * TPB));  // tid < 832
    f32x4 v7 = {0.f, 0.f, 0.f, 0.f};
    if (has8) v7 = __builtin_nontemporal_load(&p4[tid + 7 * TPB]);

    #define EXP30(x) __builtin_amdgcn_exp2f((x) * LOG2E_X30)

    // 4 independent fp32 accumulator chains (one per vector component).
    float sx, sy, sz, sw;
    sx  = EXP30(v0.x); sy  = EXP30(v0.y); sz  = EXP30(v0.z); sw  = EXP30(v0.w);
    sx += EXP30(v1.x); sy += EXP30(v1.y); sz += EXP30(v1.z); sw += EXP30(v1.w);
    sx += EXP30(v2.x); sy += EXP30(v2.y); sz += EXP30(v2.z); sw += EXP30(v2.w);
    sx += EXP30(v3.x); sy += EXP30(v3.y); sz += EXP30(v3.z); sw += EXP30(v3.w);
    sx += EXP30(v4.x); sy += EXP30(v4.y); sz += EXP30(v4.z); sw += EXP30(v4.w);
    sx += EXP30(v5.x); sy += EXP30(v5.y); sz += EXP30(v5.z); sw += EXP30(v5.w);
    sx += EXP30(v6.x); sy += EXP30(v6.y); sz += EXP30(v6.z); sw += EXP30(v6.w);
    if (has8) {
        sx += EXP30(v7.x); sy += EXP30(v7.y); sz += EXP30(v7.z); sw += EXP30(v7.w);
    }

    double sum = (double)((sx + sy) + (sz + sw));

    // wave(64) shuffle reduction in fp64
    #pragma unroll
    for (int off = 32; off > 0; off >>= 1)
        sum += __shfl_down(sum, off, 64);

    __shared__ double wave_sums[TPB / 64];
    const int wave = tid >> 6;
    const int lane = tid & 63;
    if (lane == 0) wave_sums[wave] = sum;
    __syncthreads();

    if (tid == 0) {
        double total = 0.0;
        #pragma unroll
        for (int w = 0; w < TPB / 64; ++w) total += wave_sums[w];

        const float tgt_f = rowp[labels[row]];
        // subtract the same fp32 exp term that was accumulated for the target
        const double sum_others =
            total - (double)EXP30(tgt_f);

        double t = (double)tgt_f;
        t = fmin(fmax(t, -1.0 + EPS_D), 1.0 - EPS_D);
        double theta = acos(t);
        theta = fmin(fmax(theta, EPS_D), PI_D - EPS_D);
        const double numerator = SCALE_D * (cos(theta + ARC_MARGIN_D) - COS_MARGIN_D);
        const double denominator = exp(numerator) + sum_others;
        row_terms[row] = (float)(numerator - log(denominator));
    }
}

// Reduce the 2048 per-row terms to -mean.
__global__ __launch_bounds__(256) void cosarc_reduce_kernel(
    const float* __restrict__ row_terms,
    float*       __restrict__ out)
{
    const int tid = threadIdx.x;
    double s = 0.0;
    for (int i = tid; i < B_ROWS; i += 256)
        s += (double)row_terms[i];

    #pragma unroll
    for (int off = 32; off > 0; off >>= 1)
        s += __shfl_down(s, off, 64);

    __shared__ double wave_sums[4];
    if ((tid & 63) == 0) wave_sums[tid >> 6] = s;
    __syncthreads();

    if (tid == 0) {
        double total = wave_sums[0] + wave_sums[1] + wave_sums[2] + wave_sums[3];
        out[0] = (float)(-(total / (double)B_ROWS));
    }
}

extern "C" void kernel_launch(void* const* d_in, const int* in_sizes, int n_in,
                              void* d_out, int out_size, void* d_ws, size_t ws_size,
                              hipStream_t stream)
{
    const float* preds  = (const float*)d_in[0];
    const int*   labels = (const int*)d_in[1];
    float*       out    = (float*)d_out;
    float*       ws     = (float*)d_ws;   // needs B_ROWS*4 = 8 KB

    cosarc_row_kernel<<<B_ROWS, TPB, 0, stream>>>(preds, labels, ws);
    cosarc_reduce_kernel<<<1, 256, 0, stream>>>(ws, out);
}